// Round 1
// baseline (63.768 us; speedup 1.0000x reference)
//
#include <hip/hip_runtime.h>
#include <hip/hip_bf16.h>

// QFNN6: 3 independent 2-qubit subsystems. Closed-form expectation values:
//   Z_a = cos(ty_a) * cos(ty_b)
//   Z_b = cos(p1+p2)*cos(ty_b) - sin(p1+p2)*sin(ty_a)*sin(ty_b)*sin(tz_b)*cos(tz_a+p0)
// Derivation: RZ gates contribute only phases; after CNOT (control=b, target=a)
// the b-index RY(p1+p2) mixing produces the interference term
// 2*Re[sum_a chi[a][0] conj(chi[a][1])] = (1/2) sin(ty_a) sin(ty_b) sin(tz_b) cos(tz_a+p0).

__global__ __launch_bounds__(256) void qfnn6_kernel(
    const float* __restrict__ x,   // [B,12]
    const float* __restrict__ w,   // [9]
    float* __restrict__ out,       // [B,6]
    int B)
{
    int n = blockIdx.x * blockDim.x + threadIdx.x;
    if (n >= B) return;

    // coalesced 48B row load as 3x float4 (row base 48B-aligned -> 16B aligned)
    const float4* xv = reinterpret_cast<const float4*>(x + (size_t)n * 12);
    float4 v0 = xv[0];
    float4 v1 = xv[1];
    float4 v2 = xv[2];

    float a[12] = { v0.x, v0.y, v0.z, v0.w,
                    v1.x, v1.y, v1.z, v1.w,
                    v2.x, v2.y, v2.z, v2.w };

    float o[6];
#pragma unroll
    for (int s = 0; s < 3; ++s) {
        float ty_a = a[4*s + 0];
        float tz_a = a[4*s + 1];
        float ty_b = a[4*s + 2];
        float tz_b = a[4*s + 3];

        float p0 = w[3*s + 0];            // uniform -> scalar-cached
        float P  = w[3*s + 1] + w[3*s + 2];

        float sA, cA, sB, cB, sP, cP;
        __sincosf(ty_a, &sA, &cA);
        __sincosf(ty_b, &sB, &cB);
        __sincosf(P,    &sP, &cP);
        float sZb = __sinf(tz_b);
        float cZa = __cosf(tz_a + p0);

        o[2*s + 0] = cA * cB;
        o[2*s + 1] = cP * cB - sP * sA * sB * sZb * cZa;
    }

    // 24B row store as 3x float2 (row base 24B-aligned -> 8B aligned)
    float2* ov = reinterpret_cast<float2*>(out + (size_t)n * 6);
    ov[0] = make_float2(o[0], o[1]);
    ov[1] = make_float2(o[2], o[3]);
    ov[2] = make_float2(o[4], o[5]);
}

extern "C" void kernel_launch(void* const* d_in, const int* in_sizes, int n_in,
                              void* d_out, int out_size, void* d_ws, size_t ws_size,
                              hipStream_t stream)
{
    const float* x = (const float*)d_in[0];
    const float* w = (const float*)d_in[1];
    float* out = (float*)d_out;

    int B = in_sizes[0] / 12;   // 262144
    int block = 256;
    int grid = (B + block - 1) / block;
    qfnn6_kernel<<<grid, block, 0, stream>>>(x, w, out, B);
}

// Round 2
// 63.324 us; speedup vs baseline: 1.0070x; 1.0070x over previous
//
#include <hip/hip_runtime.h>
#include <hip/hip_bf16.h>

// QFNN6: 3 independent 2-qubit subsystems. Closed-form expectation values:
//   Z_a = cos(ty_a) * cos(ty_b)
//   Z_b = cos(p1+p2)*cos(ty_b) - sin(p1+p2)*sin(ty_a)*sin(ty_b)*sin(tz_b)*cos(tz_a+p0)
// (RZ phases cancel in |.|^2; CNOT + RY(p1+p2) mixing produces the interference
//  term 2*Re[sum_a chi[a][0] conj(chi[a][1])] = (1/2) sA sB sin(tz_b) cos(tz_a+p0).)
//
// Round 2: LDS-staged version for perfect per-instruction global coalescing.
// Loads: 3x float4 per thread at blockDim stride (contiguous 12 KB/block).
// Stores: 384 float4 per block at blockDim stride (contiguous 6 KB/block).

__device__ __forceinline__ void qfnn6_row(const float* __restrict__ a,
                                          const float* __restrict__ w,
                                          float* __restrict__ o)
{
#pragma unroll
    for (int s = 0; s < 3; ++s) {
        float ty_a = a[4*s + 0];
        float tz_a = a[4*s + 1];
        float ty_b = a[4*s + 2];
        float tz_b = a[4*s + 3];

        float p0 = w[3*s + 0];
        float P  = w[3*s + 1] + w[3*s + 2];

        float sA, cA, sB, cB, sP, cP;
        __sincosf(ty_a, &sA, &cA);
        __sincosf(ty_b, &sB, &cB);
        __sincosf(P,    &sP, &cP);
        float sZb = __sinf(tz_b);
        float cZa = __cosf(tz_a + p0);

        o[2*s + 0] = cA * cB;
        o[2*s + 1] = cP * cB - sP * sA * sB * sZb * cZa;
    }
}

__global__ __launch_bounds__(256) void qfnn6_kernel(
    const float* __restrict__ x,   // [B,12]
    const float* __restrict__ w,   // [9]
    float* __restrict__ out,       // [B,6]
    int B)
{
    __shared__ float4 sx[768];     // 256 rows x 48 B = 12 KB
    __shared__ float  so[1536];    // 256 rows x 24 B = 6 KB

    int tid  = threadIdx.x;
    int base = blockIdx.x * 256;   // first row handled by this block

    int nrow = B - base;
    if (nrow > 256) nrow = 256;

    // ---- stage x rows into LDS, fully coalesced float4 loads ----
    const float4* xg = reinterpret_cast<const float4*>(x) + (size_t)base * 3;
    int nv = nrow * 3;
#pragma unroll
    for (int i = tid; i < nv; i += 256) sx[i] = xg[i];
    __syncthreads();

    // ---- per-row closed-form evaluation ----
    if (tid < nrow) {
        float4 v0 = sx[tid*3 + 0];
        float4 v1 = sx[tid*3 + 1];
        float4 v2 = sx[tid*3 + 2];
        float a[12] = { v0.x, v0.y, v0.z, v0.w,
                        v1.x, v1.y, v1.z, v1.w,
                        v2.x, v2.y, v2.z, v2.w };
        float o[6];
        qfnn6_row(a, w, o);
#pragma unroll
        for (int k = 0; k < 6; ++k) so[tid*6 + k] = o[k];
    }
    __syncthreads();

    // ---- coalesced store ----
    if (nrow == 256) {
        // full block: 1536 floats = 384 float4, contiguous
        float4* og = reinterpret_cast<float4*>(out + (size_t)base * 6);
        const float4* sov = reinterpret_cast<const float4*>(so);
#pragma unroll
        for (int i = tid; i < 384; i += 256) og[i] = sov[i];
    } else {
        // tail block (not hit for B=262144): scalar stores
        int nf = nrow * 6;
        float* og = out + (size_t)base * 6;
        for (int i = tid; i < nf; i += 256) og[i] = so[i];
    }
}

extern "C" void kernel_launch(void* const* d_in, const int* in_sizes, int n_in,
                              void* d_out, int out_size, void* d_ws, size_t ws_size,
                              hipStream_t stream)
{
    const float* x = (const float*)d_in[0];
    const float* w = (const float*)d_in[1];
    float* out = (float*)d_out;

    int B = in_sizes[0] / 12;   // 262144
    int block = 256;
    int grid = (B + block - 1) / block;
    qfnn6_kernel<<<grid, block, 0, stream>>>(x, w, out, B);
}